// Round 1
// baseline (695.683 us; speedup 1.0000x reference)
//
#include <hip/hip_runtime.h>
#include <hip/hip_bf16.h>
#include <math.h>

#define M_TOK 16
#define NDIM  2048
#define DHEAD 128
#define NHEAD 16
#define PLEN  8192
#define MAXLEN 8448
#define FFN   8192
#define TC    256
#define NCH   33   // 32 cache chunks of 256 + 1 chunk of the 16 new rows
#define LN_EPS 1e-5f
#define RSQRT_D 0.08838834764831845f  // 1/sqrt(128)

// ---------------- LayerNorm: one block per row ----------------
__global__ __launch_bounds__(256) void k_ln(const float* __restrict__ X,
                                            const float* __restrict__ g,
                                            const float* __restrict__ b,
                                            float* __restrict__ out) {
    int row = blockIdx.x, tid = threadIdx.x;
    const float4* xp = (const float4*)(X + (size_t)row * NDIM);
    float4 v0 = xp[tid], v1 = xp[tid + 256];
    float s = v0.x + v0.y + v0.z + v0.w + v1.x + v1.y + v1.z + v1.w;
    float q = v0.x*v0.x + v0.y*v0.y + v0.z*v0.z + v0.w*v0.w
            + v1.x*v1.x + v1.y*v1.y + v1.z*v1.z + v1.w*v1.w;
    #pragma unroll
    for (int o = 32; o; o >>= 1) { s += __shfl_xor(s, o); q += __shfl_xor(q, o); }
    __shared__ float ls[4], lq[4];
    int wid = tid >> 6, lane = tid & 63;
    if (lane == 0) { ls[wid] = s; lq[wid] = q; }
    __syncthreads();
    s = ls[0] + ls[1] + ls[2] + ls[3];
    q = lq[0] + lq[1] + lq[2] + lq[3];
    float mu  = s * (1.f / NDIM);
    float var = q * (1.f / NDIM) - mu * mu;
    float rs  = rsqrtf(var + LN_EPS);
    float4 g0 = ((const float4*)g)[tid], g1 = ((const float4*)g)[tid + 256];
    float4 b0 = ((const float4*)b)[tid], b1 = ((const float4*)b)[tid + 256];
    float4 o0, o1;
    o0.x = (v0.x - mu) * rs * g0.x + b0.x;  o0.y = (v0.y - mu) * rs * g0.y + b0.y;
    o0.z = (v0.z - mu) * rs * g0.z + b0.z;  o0.w = (v0.w - mu) * rs * g0.w + b0.w;
    o1.x = (v1.x - mu) * rs * g1.x + b1.x;  o1.y = (v1.y - mu) * rs * g1.y + b1.y;
    o1.z = (v1.z - mu) * rs * g1.z + b1.z;  o1.w = (v1.w - mu) * rs * g1.w + b1.w;
    float4* op = (float4*)(out + (size_t)row * NDIM);
    op[tid] = o0; op[tid + 256] = o1;
}

// ---------------- fused QKV GEMV: one wave per output column ----------------
// out[m,i] = sum_j Xn[m,j] * W[i,j]; lanes = 16 m x 4 K-slices.
__global__ __launch_bounds__(256) void k_gemv_qkv(const float* __restrict__ Xn,
                                                  const float* __restrict__ Wq,
                                                  const float* __restrict__ Wk,
                                                  const float* __restrict__ Wv,
                                                  float* __restrict__ qws,
                                                  float* __restrict__ kws,
                                                  float* __restrict__ vws) {
    int wid = threadIdx.x >> 6, lane = threadIdx.x & 63;
    int col = blockIdx.x * 4 + wid;          // 0..6143
    int sel = col >> 11, i = col & 2047;
    const float* W = (sel == 0) ? Wq : (sel == 1) ? Wk : Wv;
    int m = lane & 15, ks = lane >> 4;
    const float4* wp = (const float4*)(W + (size_t)i * NDIM + ks * 512);
    const float4* xp = (const float4*)(Xn + (size_t)m * NDIM + ks * 512);
    float a0 = 0.f, a1 = 0.f, a2 = 0.f, a3 = 0.f;
    #pragma unroll 4
    for (int it = 0; it < 128; ++it) {
        float4 w = wp[it], x = xp[it];
        a0 = fmaf(w.x, x.x, a0); a1 = fmaf(w.y, x.y, a1);
        a2 = fmaf(w.z, x.z, a2); a3 = fmaf(w.w, x.w, a3);
    }
    float acc = (a0 + a1) + (a2 + a3);
    acc += __shfl_xor(acc, 16);
    acc += __shfl_xor(acc, 32);
    if (lane < 16) {
        int h = i >> 7, d = i & 127;
        float* dst = (sel == 0) ? qws : (sel == 1) ? kws : vws;
        dst[((size_t)h * 16 + lane) * DHEAD + d] = acc;   // lane == m
    }
}

// ---------------- generic GEMV + gelu (Wup) ----------------
__device__ __forceinline__ float gelu_exact(float x) {
    return 0.5f * x * (1.0f + erff(x * 0.7071067811865475f));
}

__global__ __launch_bounds__(256) void k_gemv_up(const float* __restrict__ A,   // 16 x 2048
                                                 const float* __restrict__ W,   // 8192 x 2048
                                                 float* __restrict__ out) {     // 16 x 8192
    int wid = threadIdx.x >> 6, lane = threadIdx.x & 63;
    int col = blockIdx.x * 4 + wid;          // 0..8191
    int m = lane & 15, ks = lane >> 4;
    const float4* wp = (const float4*)(W + (size_t)col * NDIM + ks * 512);
    const float4* xp = (const float4*)(A + (size_t)m * NDIM + ks * 512);
    float a0 = 0.f, a1 = 0.f, a2 = 0.f, a3 = 0.f;
    #pragma unroll 4
    for (int it = 0; it < 128; ++it) {
        float4 w = wp[it], x = xp[it];
        a0 = fmaf(w.x, x.x, a0); a1 = fmaf(w.y, x.y, a1);
        a2 = fmaf(w.z, x.z, a2); a3 = fmaf(w.w, x.w, a3);
    }
    float acc = (a0 + a1) + (a2 + a3);
    acc += __shfl_xor(acc, 16);
    acc += __shfl_xor(acc, 32);
    if (lane < 16) out[(size_t)lane * FFN + col] = gelu_exact(acc);
}

// ---------------- GEMV + residual, 2 waves per column (8-way K split) ----------------
template <int KDIM>
__global__ __launch_bounds__(256) void k_gemv_resid(const float* __restrict__ A,   // 16 x KDIM
                                                    const float* __restrict__ W,   // 2048 x KDIM
                                                    const float* __restrict__ R,   // 16 x 2048
                                                    float* __restrict__ out) {     // 16 x 2048
    __shared__ float red[2][16];
    int wid = threadIdx.x >> 6, lane = threadIdx.x & 63;
    int colLoc = wid >> 1, wcol = wid & 1;
    int col = blockIdx.x * 2 + colLoc;
    int m = lane & 15;
    int ks = (lane >> 4) + 4 * wcol;         // 0..7
    constexpr int CH = KDIM / 8;
    const float4* wp = (const float4*)(W + (size_t)col * KDIM + (size_t)ks * CH);
    const float4* xp = (const float4*)(A + (size_t)m * KDIM + (size_t)ks * CH);
    float a0 = 0.f, a1 = 0.f, a2 = 0.f, a3 = 0.f;
    #pragma unroll 4
    for (int it = 0; it < CH / 4; ++it) {
        float4 w = wp[it], x = xp[it];
        a0 = fmaf(w.x, x.x, a0); a1 = fmaf(w.y, x.y, a1);
        a2 = fmaf(w.z, x.z, a2); a3 = fmaf(w.w, x.w, a3);
    }
    float acc = (a0 + a1) + (a2 + a3);
    acc += __shfl_xor(acc, 16);
    acc += __shfl_xor(acc, 32);
    if (wcol == 1 && lane < 16) red[colLoc][lane] = acc;
    __syncthreads();
    if (wcol == 0 && lane < 16) {
        float t = acc + red[colLoc][lane];
        out[(size_t)lane * NDIM + col] = R[(size_t)lane * NDIM + col] + t;
    }
}

// ---------------- attention: one block per (head, T-chunk), flash-decode partials ----------------
__global__ __launch_bounds__(256) void k_attn(const float* __restrict__ cacheK,
                                              const float* __restrict__ cacheV,
                                              const float* __restrict__ qws,
                                              const float* __restrict__ kws,
                                              const float* __restrict__ vws,
                                              float* __restrict__ part,   // [16h][33c][16m][128d]
                                              float* __restrict__ ms) {   // [16h][33c][16m][2]
    __shared__ float s_lds[TC * 16];
    int bid = blockIdx.x;
    int h = bid / NCH, c = bid % NCH;
    int nT = (c < 32) ? TC : M_TOK;
    const float* Kbase = (c < 32) ? cacheK + ((size_t)h * MAXLEN + (size_t)c * TC) * DHEAD
                                  : kws + (size_t)h * M_TOK * DHEAD;
    const float* Vbase = (c < 32) ? cacheV + ((size_t)h * MAXLEN + (size_t)c * TC) * DHEAD
                                  : vws + (size_t)h * M_TOK * DHEAD;
    int wid = threadIdx.x >> 6, lane = threadIdx.x & 63;
    int m = lane & 15, ds = lane >> 4;

    // q fragment in registers: q[h][m][ds*32 .. ds*32+31]
    float4 qf[8];
    const float4* qp = (const float4*)(qws + ((size_t)h * M_TOK + m) * DHEAD + ds * 32);
    #pragma unroll
    for (int it = 0; it < 8; ++it) qf[it] = qp[it];

    // phase 1: scores
    for (int t = wid; t < nT; t += 4) {
        const float4* kp = (const float4*)(Kbase + (size_t)t * DHEAD + ds * 32);
        float a0 = 0.f, a1 = 0.f, a2 = 0.f, a3 = 0.f;
        #pragma unroll
        for (int it = 0; it < 8; ++it) {
            float4 kv = kp[it];
            a0 = fmaf(kv.x, qf[it].x, a0); a1 = fmaf(kv.y, qf[it].y, a1);
            a2 = fmaf(kv.z, qf[it].z, a2); a3 = fmaf(kv.w, qf[it].w, a3);
        }
        float acc = (a0 + a1) + (a2 + a3);
        acc += __shfl_xor(acc, 16);
        acc += __shfl_xor(acc, 32);
        if (lane < 16) s_lds[t * 16 + lane] = acc * RSQRT_D;
    }
    __syncthreads();

    // phase 2: chunk-local softmax (p values left in LDS, max/sum to ws)
    int m2 = threadIdx.x >> 4, tl = threadIdx.x & 15;
    float mx = -1e30f;
    for (int t = tl; t < nT; t += 16) mx = fmaxf(mx, s_lds[t * 16 + m2]);
    #pragma unroll
    for (int o = 8; o; o >>= 1) mx = fmaxf(mx, __shfl_xor(mx, o));
    float sm = 0.f;
    for (int t = tl; t < nT; t += 16) {
        float p = expf(s_lds[t * 16 + m2] - mx);
        s_lds[t * 16 + m2] = p;
        sm += p;
    }
    #pragma unroll
    for (int o = 8; o; o >>= 1) sm += __shfl_xor(sm, o);
    if (tl == 0) {
        float* msp = ms + ((size_t)(h * NCH + c) * 16 + m2) * 2;
        msp[0] = mx; msp[1] = sm;
    }
    __syncthreads();

    // phase 3: partial PV. wave wid -> m in [4*wid, 4*wid+4); lanes cover d (float2 each)
    float2 acc2[4] = {{0.f,0.f},{0.f,0.f},{0.f,0.f},{0.f,0.f}};
    for (int t = 0; t < nT; ++t) {
        float2 v = *(const float2*)(Vbase + (size_t)t * DHEAD + 2 * lane);
        #pragma unroll
        for (int mm = 0; mm < 4; ++mm) {
            float p = s_lds[t * 16 + wid * 4 + mm];
            acc2[mm].x = fmaf(p, v.x, acc2[mm].x);
            acc2[mm].y = fmaf(p, v.y, acc2[mm].y);
        }
    }
    #pragma unroll
    for (int mm = 0; mm < 4; ++mm) {
        float* dp = part + ((size_t)(h * NCH + c) * 16 + wid * 4 + mm) * DHEAD + 2 * lane;
        dp[0] = acc2[mm].x; dp[1] = acc2[mm].y;
    }
}

// ---------------- combine chunk partials (LSE merge), transpose to (m, h*128+d) ----------------
__global__ __launch_bounds__(256) void k_combine(const float* __restrict__ part,
                                                 const float* __restrict__ ms,
                                                 float* __restrict__ attnout) {
    __shared__ float scale[16][NCH];
    int h = blockIdx.x, tid = threadIdx.x;
    if (tid < 16) {
        int m = tid;
        float gmax = -1e30f;
        for (int c = 0; c < NCH; ++c)
            gmax = fmaxf(gmax, ms[((size_t)(h * NCH + c) * 16 + m) * 2]);
        float denom = 0.f;
        for (int c = 0; c < NCH; ++c) {
            const float* msp = ms + ((size_t)(h * NCH + c) * 16 + m) * 2;
            denom += msp[1] * expf(msp[0] - gmax);
        }
        float inv = 1.f / denom;
        for (int c = 0; c < NCH; ++c) {
            const float* msp = ms + ((size_t)(h * NCH + c) * 16 + m) * 2;
            scale[m][c] = expf(msp[0] - gmax) * inv;
        }
    }
    __syncthreads();
    for (int idx = tid; idx < M_TOK * DHEAD; idx += 256) {
        int m = idx >> 7, d = idx & 127;
        float acc = 0.f;
        for (int c = 0; c < NCH; ++c)
            acc = fmaf(part[((size_t)(h * NCH + c) * 16 + m) * DHEAD + d], scale[m][c], acc);
        attnout[(size_t)m * NDIM + h * DHEAD + d] = acc;
    }
}

// ---------------- launcher ----------------
extern "C" void kernel_launch(void* const* d_in, const int* in_sizes, int n_in,
                              void* d_out, int out_size, void* d_ws, size_t ws_size,
                              hipStream_t stream) {
    const float* X      = (const float*)d_in[0];
    const float* ln1_g  = (const float*)d_in[1];
    const float* ln1_b  = (const float*)d_in[2];
    const float* Wq     = (const float*)d_in[3];
    const float* Wk     = (const float*)d_in[4];
    const float* Wv     = (const float*)d_in[5];
    const float* Wo     = (const float*)d_in[6];
    const float* ln2_g  = (const float*)d_in[7];
    const float* ln2_b  = (const float*)d_in[8];
    const float* Wup    = (const float*)d_in[9];
    const float* Wdown  = (const float*)d_in[10];
    const float* cacheK = (const float*)d_in[11];
    const float* cacheV = (const float*)d_in[12];
    float* out = (float*)d_out;

    float* ws = (float*)d_ws;
    float* Xn1   = ws;                       // 32768
    float* qws   = Xn1 + 32768;              // 32768
    float* kws   = qws + 32768;              // 32768
    float* vws   = kws + 32768;              // 32768
    float* partb = vws + 32768;              // 16*33*16*128 = 1081344
    float* msb   = partb + 1081344;          // 16*33*16*2   = 16896
    float* attnо = msb + 16896;              // 32768
    float* X2    = attnо + 32768;            // 32768
    float* Xn2   = X2 + 32768;               // 32768
    float* ffnh  = Xn2 + 32768;              // 16*8192 = 131072

    k_ln<<<M_TOK, 256, 0, stream>>>(X, ln1_g, ln1_b, Xn1);
    k_gemv_qkv<<<(3 * NDIM) / 4, 256, 0, stream>>>(Xn1, Wq, Wk, Wv, qws, kws, vws);
    k_attn<<<NHEAD * NCH, 256, 0, stream>>>(cacheK, cacheV, qws, kws, vws, partb, msb);
    k_combine<<<NHEAD, 256, 0, stream>>>(partb, msb, attnо);
    k_gemv_resid<2048><<<NDIM / 2, 256, 0, stream>>>(attnо, Wo, X, X2);
    k_ln<<<M_TOK, 256, 0, stream>>>(X2, ln2_g, ln2_b, Xn2);
    k_gemv_up<<<FFN / 4, 256, 0, stream>>>(Xn2, Wup, ffnh);
    k_gemv_resid<8192><<<NDIM / 2, 256, 0, stream>>>(ffnh, Wdown, X2, out);
}

// Round 2
// 362.336 us; speedup vs baseline: 1.9200x; 1.9200x over previous
//
#include <hip/hip_runtime.h>
#include <hip/hip_bf16.h>
#include <math.h>

#define M_TOK 16
#define NDIM  2048
#define DHEAD 128
#define NHEAD 16
#define MAXLEN 8448
#define FFN   8192
#define TC    256
#define NCH   33   // 32 cache chunks of 256 + 1 chunk of the 16 new rows
#define LN_EPS 1e-5f
#define RSQRT_D 0.08838834764831845f  // 1/sqrt(128)

// ================= fold reduce: 64-lane partial sums -> one output per lane ==
// After fold64: lane L holds sum over all 64 lanes of v[L].
// After fold32: lane L holds sum over all 64 lanes of v[(L>>1)&31] (pairs duplicate).
template<int H>
__device__ __forceinline__ void fold_step(float* v, int lane, int o) {
    bool hi = (lane & o) != 0;
    #pragma unroll
    for (int i = 0; i < H; ++i) {
        float send = hi ? v[i] : v[i + H];
        float keep = hi ? v[i + H] : v[i];
        v[i] = keep + __shfl_xor(send, o);
    }
}

__device__ __forceinline__ void fold64(float* v, int lane) {
    fold_step<32>(v, lane, 32);
    fold_step<16>(v, lane, 16);
    fold_step<8>(v, lane, 8);
    fold_step<4>(v, lane, 4);
    fold_step<2>(v, lane, 2);
    fold_step<1>(v, lane, 1);
}

__device__ __forceinline__ void fold32(float* v, int lane) {
    fold_step<16>(v, lane, 32);
    fold_step<8>(v, lane, 16);
    fold_step<4>(v, lane, 8);
    fold_step<2>(v, lane, 4);
    fold_step<1>(v, lane, 2);
    v[0] += __shfl_xor(v[0], 1);
}

// ================= GEMV core: 16 x KDIM activations, NCPW cols per wave =======
// All loads fully coalesced (1KB per wave instruction). Lane accumulates
// partials for all 16 m and NCPW cols over its k-slice (lane*4 within each
// 256-float chunk); fold later.
template<int KDIM, int NCPW>
__device__ __forceinline__ void gemv16_core(const float* __restrict__ A,
                                            const float* __restrict__ W,
                                            int col0, int lane, float* v) {
    const float* wp = W + (size_t)col0 * KDIM + lane * 4;
    const float* ap = A + lane * 4;
    #pragma unroll 1
    for (int kc = 0; kc < KDIM; kc += 256) {
        float4 xr[16];
        #pragma unroll
        for (int m = 0; m < 16; ++m)
            xr[m] = *(const float4*)(ap + (size_t)m * KDIM + kc);
        #pragma unroll
        for (int c = 0; c < NCPW; ++c) {
            float4 w = *(const float4*)(wp + (size_t)c * KDIM + kc);
            #pragma unroll
            for (int m = 0; m < 16; ++m) {
                v[m * NCPW + c] = fmaf(w.x, xr[m].x, v[m * NCPW + c]);
                v[m * NCPW + c] = fmaf(w.y, xr[m].y, v[m * NCPW + c]);
                v[m * NCPW + c] = fmaf(w.z, xr[m].z, v[m * NCPW + c]);
                v[m * NCPW + c] = fmaf(w.w, xr[m].w, v[m * NCPW + c]);
            }
        }
    }
}

// ---------------- fused QKV GEMV ----------------
__global__ __launch_bounds__(256) void k_qkv(const float* __restrict__ Xn,
                                             const float* __restrict__ Wq,
                                             const float* __restrict__ Wk,
                                             const float* __restrict__ Wv,
                                             float* __restrict__ qws,
                                             float* __restrict__ kws,
                                             float* __restrict__ vws) {
    int tid = threadIdx.x, wid = tid >> 6, lane = tid & 63;
    int b = blockIdx.x;                    // 0..383
    int sel = b >> 7;                      // 128 blocks per matrix
    int cb = (b & 127) * 16 + wid * 4;     // wave's col base within 2048
    const float* W = (sel == 0) ? Wq : (sel == 1) ? Wk : Wv;
    float* dst = (sel == 0) ? qws : (sel == 1) ? kws : vws;
    float v[64];
    #pragma unroll
    for (int i = 0; i < 64; ++i) v[i] = 0.f;
    gemv16_core<2048, 4>(Xn, W, cb, lane, v);
    fold64(v, lane);
    int m = lane >> 2, c = lane & 3;
    int gcol = cb + c;
    int h = gcol >> 7, d = gcol & 127;
    dst[(((size_t)h * 16 + m) << 7) + d] = v[0];
}

// ---------------- Wup GEMV + gelu ----------------
__device__ __forceinline__ float gelu_exact(float x) {
    return 0.5f * x * (1.0f + erff(x * 0.7071067811865475f));
}

__global__ __launch_bounds__(256) void k_up(const float* __restrict__ A,
                                            const float* __restrict__ W,
                                            float* __restrict__ out) {
    int tid = threadIdx.x, wid = tid >> 6, lane = tid & 63;
    int cb = blockIdx.x * 16 + wid * 4;    // 512 blocks -> 8192 cols
    float v[64];
    #pragma unroll
    for (int i = 0; i < 64; ++i) v[i] = 0.f;
    gemv16_core<2048, 4>(A, W, cb, lane, v);
    fold64(v, lane);
    int m = lane >> 2, c = lane & 3;
    out[(size_t)m * FFN + cb + c] = gelu_exact(v[0]);
}

// ---------------- GEMV + residual ----------------
template<int KDIM>
__global__ __launch_bounds__(256) void k_resid(const float* __restrict__ A,
                                               const float* __restrict__ W,
                                               const float* __restrict__ R,
                                               float* __restrict__ out) {
    int tid = threadIdx.x, wid = tid >> 6, lane = tid & 63;
    int cb = blockIdx.x * 8 + wid * 2;     // 256 blocks -> 2048 cols
    float v[32];
    #pragma unroll
    for (int i = 0; i < 32; ++i) v[i] = 0.f;
    gemv16_core<KDIM, 2>(A, W, cb, lane, v);
    fold32(v, lane);
    int idx = (lane >> 1) & 31;
    int m = idx >> 1, c = idx & 1;
    if ((lane & 1) == 0) {
        int col = cb + c;
        out[(size_t)m * NDIM + col] = R[(size_t)m * NDIM + col] + v[0];
    }
}

// ---------------- LayerNorm: one block per row ----------------
__global__ __launch_bounds__(256) void k_ln(const float* __restrict__ X,
                                            const float* __restrict__ g,
                                            const float* __restrict__ b,
                                            float* __restrict__ out) {
    int row = blockIdx.x, tid = threadIdx.x;
    const float4* xp = (const float4*)(X + (size_t)row * NDIM);
    float4 v0 = xp[tid], v1 = xp[tid + 256];
    float s = v0.x + v0.y + v0.z + v0.w + v1.x + v1.y + v1.z + v1.w;
    float q = v0.x*v0.x + v0.y*v0.y + v0.z*v0.z + v0.w*v0.w
            + v1.x*v1.x + v1.y*v1.y + v1.z*v1.z + v1.w*v1.w;
    #pragma unroll
    for (int o = 32; o; o >>= 1) { s += __shfl_xor(s, o); q += __shfl_xor(q, o); }
    __shared__ float ls[4], lq[4];
    int wid = tid >> 6, lane = tid & 63;
    if (lane == 0) { ls[wid] = s; lq[wid] = q; }
    __syncthreads();
    s = ls[0] + ls[1] + ls[2] + ls[3];
    q = lq[0] + lq[1] + lq[2] + lq[3];
    float mu  = s * (1.f / NDIM);
    float var = q * (1.f / NDIM) - mu * mu;
    float rs  = rsqrtf(var + LN_EPS);
    float4 g0 = ((const float4*)g)[tid], g1 = ((const float4*)g)[tid + 256];
    float4 b0 = ((const float4*)b)[tid], b1 = ((const float4*)b)[tid + 256];
    float4 o0, o1;
    o0.x = (v0.x - mu) * rs * g0.x + b0.x;  o0.y = (v0.y - mu) * rs * g0.y + b0.y;
    o0.z = (v0.z - mu) * rs * g0.z + b0.z;  o0.w = (v0.w - mu) * rs * g0.w + b0.w;
    o1.x = (v1.x - mu) * rs * g1.x + b1.x;  o1.y = (v1.y - mu) * rs * g1.y + b1.y;
    o1.z = (v1.z - mu) * rs * g1.z + b1.z;  o1.w = (v1.w - mu) * rs * g1.w + b1.w;
    float4* op = (float4*)(out + (size_t)row * NDIM);
    op[tid] = o0; op[tid + 256] = o1;
}

// ---------------- attention: one block per (head, T-chunk), flash-decode partials ----------------
__global__ __launch_bounds__(256) void k_attn(const float* __restrict__ cacheK,
                                              const float* __restrict__ cacheV,
                                              const float* __restrict__ qws,
                                              const float* __restrict__ kws,
                                              const float* __restrict__ vws,
                                              float* __restrict__ part,   // [16h][33c][16m][128d]
                                              float* __restrict__ ms) {   // [16h][33c][16m][2]
    __shared__ float s_lds[TC * 16];
    int bid = blockIdx.x;
    int h = bid / NCH, c = bid % NCH;
    int nT = (c < 32) ? TC : M_TOK;
    const float* Kbase = (c < 32) ? cacheK + ((size_t)h * MAXLEN + (size_t)c * TC) * DHEAD
                                  : kws + (size_t)h * M_TOK * DHEAD;
    const float* Vbase = (c < 32) ? cacheV + ((size_t)h * MAXLEN + (size_t)c * TC) * DHEAD
                                  : vws + (size_t)h * M_TOK * DHEAD;
    int wid = threadIdx.x >> 6, lane = threadIdx.x & 63;
    int m = lane & 15, ds = lane >> 4;

    float4 qf[8];
    const float4* qp = (const float4*)(qws + ((size_t)h * M_TOK + m) * DHEAD + ds * 32);
    #pragma unroll
    for (int it = 0; it < 8; ++it) qf[it] = qp[it];

    // phase 1: scores
    for (int t = wid; t < nT; t += 4) {
        const float4* kp = (const float4*)(Kbase + (size_t)t * DHEAD + ds * 32);
        float a0 = 0.f, a1 = 0.f, a2 = 0.f, a3 = 0.f;
        #pragma unroll
        for (int it = 0; it < 8; ++it) {
            float4 kv = kp[it];
            a0 = fmaf(kv.x, qf[it].x, a0); a1 = fmaf(kv.y, qf[it].y, a1);
            a2 = fmaf(kv.z, qf[it].z, a2); a3 = fmaf(kv.w, qf[it].w, a3);
        }
        float acc = (a0 + a1) + (a2 + a3);
        acc += __shfl_xor(acc, 16);
        acc += __shfl_xor(acc, 32);
        if (lane < 16) s_lds[t * 16 + lane] = acc * RSQRT_D;
    }
    __syncthreads();

    // phase 2: chunk-local softmax
    int m2 = threadIdx.x >> 4, tl = threadIdx.x & 15;
    float mx = -1e30f;
    for (int t = tl; t < nT; t += 16) mx = fmaxf(mx, s_lds[t * 16 + m2]);
    #pragma unroll
    for (int o = 8; o; o >>= 1) mx = fmaxf(mx, __shfl_xor(mx, o));
    float sm = 0.f;
    for (int t = tl; t < nT; t += 16) {
        float p = expf(s_lds[t * 16 + m2] - mx);
        s_lds[t * 16 + m2] = p;
        sm += p;
    }
    #pragma unroll
    for (int o = 8; o; o >>= 1) sm += __shfl_xor(sm, o);
    if (tl == 0) {
        float* msp = ms + ((size_t)(h * NCH + c) * 16 + m2) * 2;
        msp[0] = mx; msp[1] = sm;
    }
    __syncthreads();

    // phase 3: partial PV
    float2 acc2[4] = {{0.f,0.f},{0.f,0.f},{0.f,0.f},{0.f,0.f}};
    for (int t = 0; t < nT; ++t) {
        float2 vv = *(const float2*)(Vbase + (size_t)t * DHEAD + 2 * lane);
        #pragma unroll
        for (int mm = 0; mm < 4; ++mm) {
            float p = s_lds[t * 16 + wid * 4 + mm];
            acc2[mm].x = fmaf(p, vv.x, acc2[mm].x);
            acc2[mm].y = fmaf(p, vv.y, acc2[mm].y);
        }
    }
    #pragma unroll
    for (int mm = 0; mm < 4; ++mm) {
        float* dp = part + ((size_t)(h * NCH + c) * 16 + wid * 4 + mm) * DHEAD + 2 * lane;
        dp[0] = acc2[mm].x; dp[1] = acc2[mm].y;
    }
}

// ---------------- combine chunk partials ----------------
__global__ __launch_bounds__(256) void k_combine(const float* __restrict__ part,
                                                 const float* __restrict__ ms,
                                                 float* __restrict__ attnout) {
    __shared__ float scale[16][NCH];
    int h = blockIdx.x, tid = threadIdx.x;
    if (tid < 16) {
        int m = tid;
        float gmax = -1e30f;
        for (int c = 0; c < NCH; ++c)
            gmax = fmaxf(gmax, ms[((size_t)(h * NCH + c) * 16 + m) * 2]);
        float denom = 0.f;
        for (int c = 0; c < NCH; ++c) {
            const float* msp = ms + ((size_t)(h * NCH + c) * 16 + m) * 2;
            denom += msp[1] * expf(msp[0] - gmax);
        }
        float inv = 1.f / denom;
        for (int c = 0; c < NCH; ++c) {
            const float* msp = ms + ((size_t)(h * NCH + c) * 16 + m) * 2;
            scale[m][c] = expf(msp[0] - gmax) * inv;
        }
    }
    __syncthreads();
    for (int idx = tid; idx < M_TOK * DHEAD; idx += 256) {
        int m = idx >> 7, d = idx & 127;
        float acc = 0.f;
        for (int c = 0; c < NCH; ++c)
            acc = fmaf(part[((size_t)(h * NCH + c) * 16 + m) * DHEAD + d], scale[m][c], acc);
        attnout[(size_t)m * NDIM + h * DHEAD + d] = acc;
    }
}

// ---------------- launcher ----------------
extern "C" void kernel_launch(void* const* d_in, const int* in_sizes, int n_in,
                              void* d_out, int out_size, void* d_ws, size_t ws_size,
                              hipStream_t stream) {
    const float* X      = (const float*)d_in[0];
    const float* ln1_g  = (const float*)d_in[1];
    const float* ln1_b  = (const float*)d_in[2];
    const float* Wq     = (const float*)d_in[3];
    const float* Wk     = (const float*)d_in[4];
    const float* Wv     = (const float*)d_in[5];
    const float* Wo     = (const float*)d_in[6];
    const float* ln2_g  = (const float*)d_in[7];
    const float* ln2_b  = (const float*)d_in[8];
    const float* Wup    = (const float*)d_in[9];
    const float* Wdown  = (const float*)d_in[10];
    const float* cacheK = (const float*)d_in[11];
    const float* cacheV = (const float*)d_in[12];
    float* out = (float*)d_out;

    float* ws = (float*)d_ws;
    float* Xn1    = ws;                       // 32768
    float* qws    = Xn1 + 32768;              // 32768
    float* kws    = qws + 32768;              // 32768
    float* vws    = kws + 32768;              // 32768
    float* partb  = vws + 32768;              // 16*33*16*128 = 1081344
    float* msb    = partb + 1081344;          // 16*33*16*2   = 16896
    float* attn_o = msb + 16896;              // 32768
    float* X2     = attn_o + 32768;           // 32768
    float* Xn2    = X2 + 32768;               // 32768
    float* ffnh   = Xn2 + 32768;              // 16*8192 = 131072

    k_ln<<<M_TOK, 256, 0, stream>>>(X, ln1_g, ln1_b, Xn1);
    k_qkv<<<384, 256, 0, stream>>>(Xn1, Wq, Wk, Wv, qws, kws, vws);
    k_attn<<<NHEAD * NCH, 256, 0, stream>>>(cacheK, cacheV, qws, kws, vws, partb, msb);
    k_combine<<<NHEAD, 256, 0, stream>>>(partb, msb, attn_o);
    k_resid<2048><<<256, 256, 0, stream>>>(attn_o, Wo, X, X2);
    k_ln<<<M_TOK, 256, 0, stream>>>(X2, ln2_g, ln2_b, Xn2);
    k_up<<<512, 256, 0, stream>>>(Xn2, Wup, ffnh);
    k_resid<8192><<<256, 256, 0, stream>>>(ffnh, Wdown, X2, out);
}

// Round 3
// 165.239 us; speedup vs baseline: 4.2102x; 2.1928x over previous
//
#include <hip/hip_runtime.h>
#include <hip/hip_bf16.h>
#include <math.h>

#define M_TOK 16
#define NDIM  2048
#define DHEAD 128
#define NHEAD 16
#define MAXLEN 8448
#define FFN   8192
#define TC    128
#define NCH   65   // 64 cache chunks of 128 + 1 chunk of the 16 new rows
#define LN_EPS 1e-5f
#define RSQRT_D 0.08838834764831845f  // 1/sqrt(128)

// ================= fold reduce: 64-lane partial sums -> one output per lane ==
template<int H>
__device__ __forceinline__ void fold_step(float* v, int lane, int o) {
    bool hi = (lane & o) != 0;
    #pragma unroll
    for (int i = 0; i < H; ++i) {
        float send = hi ? v[i] : v[i + H];
        float keep = hi ? v[i + H] : v[i];
        v[i] = keep + __shfl_xor(send, o);
    }
}

__device__ __forceinline__ void fold64(float* v, int lane) {
    fold_step<32>(v, lane, 32);
    fold_step<16>(v, lane, 16);
    fold_step<8>(v, lane, 8);
    fold_step<4>(v, lane, 4);
    fold_step<2>(v, lane, 2);
    fold_step<1>(v, lane, 1);
}

// ================= split-K GEMV core =========================================
// Block: 4 waves, all on the SAME 4 columns; wave w owns k-range
// [w*KDIM/4, (w+1)*KDIM/4). All loads fully coalesced (1KB/instr).
// After fold64, lane L of each wave holds its partial for (m=L>>2, c=L&3);
// cross-wave reduce via LDS.
template<int KDIM>
__device__ __forceinline__ void gemv_splitk(const float* __restrict__ A,
                                            const float* __restrict__ W,
                                            int col0, int wid, int lane,
                                            float* v) {
    const int kbase = wid * (KDIM / 4);
    const float* wp = W + (size_t)col0 * KDIM + kbase + lane * 4;
    const float* ap = A + kbase + lane * 4;
    #pragma unroll 1
    for (int kc = 0; kc < KDIM / 4; kc += 256) {
        float4 w4[4];
        #pragma unroll
        for (int c = 0; c < 4; ++c)
            w4[c] = *(const float4*)(wp + (size_t)c * KDIM + kc);
        #pragma unroll
        for (int m = 0; m < 16; ++m) {
            float4 x4 = *(const float4*)(ap + (size_t)m * KDIM + kc);
            #pragma unroll
            for (int c = 0; c < 4; ++c) {
                v[m * 4 + c] = fmaf(w4[c].x, x4.x, v[m * 4 + c]);
                v[m * 4 + c] = fmaf(w4[c].y, x4.y, v[m * 4 + c]);
                v[m * 4 + c] = fmaf(w4[c].z, x4.z, v[m * 4 + c]);
                v[m * 4 + c] = fmaf(w4[c].w, x4.w, v[m * 4 + c]);
            }
        }
    }
}

// returns summed value for this lane's (m,c) on wave 0; others return garbage
__device__ __forceinline__ float crosswave_reduce(float val, int wid, int lane,
                                                  float (*s_red)[64]) {
    if (wid != 0) s_red[wid - 1][lane] = val;
    __syncthreads();
    return val + s_red[0][lane] + s_red[1][lane] + s_red[2][lane];
}

// ---------------- fused QKV GEMV ----------------
__global__ __launch_bounds__(256) void k_qkv(const float* __restrict__ Xn,
                                             const float* __restrict__ Wq,
                                             const float* __restrict__ Wk,
                                             const float* __restrict__ Wv,
                                             float* __restrict__ qws,
                                             float* __restrict__ kws,
                                             float* __restrict__ vws) {
    __shared__ float s_red[3][64];
    int tid = threadIdx.x, wid = tid >> 6, lane = tid & 63;
    int b = blockIdx.x;                    // 0..1535
    int sel = b >> 9;                      // 512 blocks per matrix
    int cb = (b & 511) * 4;
    const float* W = (sel == 0) ? Wq : (sel == 1) ? Wk : Wv;
    float* dst = (sel == 0) ? qws : (sel == 1) ? kws : vws;
    float v[64];
    #pragma unroll
    for (int i = 0; i < 64; ++i) v[i] = 0.f;
    gemv_splitk<2048>(Xn, W, cb, wid, lane, v);
    fold64(v, lane);
    float r = crosswave_reduce(v[0], wid, lane, s_red);
    if (wid == 0) {
        int m = lane >> 2, c = lane & 3;
        int gcol = cb + c;
        int h = gcol >> 7, d = gcol & 127;
        dst[(((size_t)h * 16 + m) << 7) + d] = r;
    }
}

// ---------------- Wup GEMV + gelu ----------------
__device__ __forceinline__ float gelu_exact(float x) {
    return 0.5f * x * (1.0f + erff(x * 0.7071067811865475f));
}

__global__ __launch_bounds__(256) void k_up(const float* __restrict__ A,
                                            const float* __restrict__ W,
                                            float* __restrict__ out) {
    __shared__ float s_red[3][64];
    int tid = threadIdx.x, wid = tid >> 6, lane = tid & 63;
    int cb = blockIdx.x * 4;               // 2048 blocks
    float v[64];
    #pragma unroll
    for (int i = 0; i < 64; ++i) v[i] = 0.f;
    gemv_splitk<2048>(A, W, cb, wid, lane, v);
    fold64(v, lane);
    float r = crosswave_reduce(v[0], wid, lane, s_red);
    if (wid == 0) {
        int m = lane >> 2, c = lane & 3;
        out[(size_t)m * FFN + cb + c] = gelu_exact(r);
    }
}

// ---------------- GEMV + residual ----------------
template<int KDIM>
__global__ __launch_bounds__(256) void k_resid(const float* __restrict__ A,
                                               const float* __restrict__ W,
                                               const float* __restrict__ R,
                                               float* __restrict__ out) {
    __shared__ float s_red[3][64];
    int tid = threadIdx.x, wid = tid >> 6, lane = tid & 63;
    int cb = blockIdx.x * 4;               // 512 blocks
    float v[64];
    #pragma unroll
    for (int i = 0; i < 64; ++i) v[i] = 0.f;
    gemv_splitk<KDIM>(A, W, cb, wid, lane, v);
    fold64(v, lane);
    float r = crosswave_reduce(v[0], wid, lane, s_red);
    if (wid == 0) {
        int m = lane >> 2, c = lane & 3;
        int col = cb + c;
        out[(size_t)m * NDIM + col] = R[(size_t)m * NDIM + col] + r;
    }
}

// ---------------- LayerNorm: one block per row ----------------
__global__ __launch_bounds__(256) void k_ln(const float* __restrict__ X,
                                            const float* __restrict__ g,
                                            const float* __restrict__ b,
                                            float* __restrict__ out) {
    int row = blockIdx.x, tid = threadIdx.x;
    const float4* xp = (const float4*)(X + (size_t)row * NDIM);
    float4 v0 = xp[tid], v1 = xp[tid + 256];
    float s = v0.x + v0.y + v0.z + v0.w + v1.x + v1.y + v1.z + v1.w;
    float q = v0.x*v0.x + v0.y*v0.y + v0.z*v0.z + v0.w*v0.w
            + v1.x*v1.x + v1.y*v1.y + v1.z*v1.z + v1.w*v1.w;
    #pragma unroll
    for (int o = 32; o; o >>= 1) { s += __shfl_xor(s, o); q += __shfl_xor(q, o); }
    __shared__ float ls[4], lq[4];
    int wid = tid >> 6, lane = tid & 63;
    if (lane == 0) { ls[wid] = s; lq[wid] = q; }
    __syncthreads();
    s = ls[0] + ls[1] + ls[2] + ls[3];
    q = lq[0] + lq[1] + lq[2] + lq[3];
    float mu  = s * (1.f / NDIM);
    float var = q * (1.f / NDIM) - mu * mu;
    float rs  = rsqrtf(var + LN_EPS);
    float4 g0 = ((const float4*)g)[tid], g1 = ((const float4*)g)[tid + 256];
    float4 b0 = ((const float4*)b)[tid], b1 = ((const float4*)b)[tid + 256];
    float4 o0, o1;
    o0.x = (v0.x - mu) * rs * g0.x + b0.x;  o0.y = (v0.y - mu) * rs * g0.y + b0.y;
    o0.z = (v0.z - mu) * rs * g0.z + b0.z;  o0.w = (v0.w - mu) * rs * g0.w + b0.w;
    o1.x = (v1.x - mu) * rs * g1.x + b1.x;  o1.y = (v1.y - mu) * rs * g1.y + b1.y;
    o1.z = (v1.z - mu) * rs * g1.z + b1.z;  o1.w = (v1.w - mu) * rs * g1.w + b1.w;
    float4* op = (float4*)(out + (size_t)row * NDIM);
    op[tid] = o0; op[tid + 256] = o1;
}

// ---------------- attention: block per (head, 128-row chunk) ----------------
__global__ __launch_bounds__(256) void k_attn(const float* __restrict__ cacheK,
                                              const float* __restrict__ cacheV,
                                              const float* __restrict__ qws,
                                              const float* __restrict__ kws,
                                              const float* __restrict__ vws,
                                              float* __restrict__ part,   // [16h][65c][16m][128d]
                                              float* __restrict__ ms) {   // [16h][65c][16m][2]
    __shared__ float s_q[16 * DHEAD];      // 8 KB
    __shared__ float s_p[16][TC];          // 8 KB, scores transposed [m][t]
    int bid = blockIdx.x;
    int h = bid / NCH, c = bid % NCH;
    int nT = (c < NCH - 1) ? TC : M_TOK;
    const float* Kb = (c < NCH - 1) ? cacheK + ((size_t)h * MAXLEN + (size_t)c * TC) * DHEAD
                                    : kws + (size_t)h * M_TOK * DHEAD;
    const float* Vb = (c < NCH - 1) ? cacheV + ((size_t)h * MAXLEN + (size_t)c * TC) * DHEAD
                                    : vws + (size_t)h * M_TOK * DHEAD;
    int tid = threadIdx.x, wid = tid >> 6, lane = tid & 63;

    // stage q for this head (2048 floats)
    {
        const float4* qp = (const float4*)(qws + (size_t)h * M_TOK * DHEAD);
        float4* sq = (float4*)s_q;
        sq[tid] = qp[tid];
        sq[tid + 256] = qp[tid + 256];
    }
    __syncthreads();

    int tloc = lane & 15, ds = lane >> 4;

    // ---- phase 1: scores, wave handles 32 t rows (two 16-row subtiles) ----
    if (nT == TC) {
        int t0 = wid * 32;
        const float4* kp0 = (const float4*)(Kb + (size_t)(t0 + tloc) * DHEAD + ds * 32);
        const float4* kp1 = (const float4*)(Kb + (size_t)(t0 + 16 + tloc) * DHEAD + ds * 32);
        float4 k0[8], k1[8];
        #pragma unroll
        for (int i = 0; i < 8; ++i) k0[i] = kp0[i];
        #pragma unroll
        for (int i = 0; i < 8; ++i) k1[i] = kp1[i];
        #pragma unroll 4
        for (int m = 0; m < 16; ++m) {
            const float4* qp4 = (const float4*)(s_q + m * DHEAD + ds * 32);
            float a00 = 0.f, a01 = 0.f, a02 = 0.f, a03 = 0.f;
            float a10 = 0.f, a11 = 0.f, a12 = 0.f, a13 = 0.f;
            #pragma unroll
            for (int i = 0; i < 8; ++i) {
                float4 q4 = qp4[i];
                a00 = fmaf(k0[i].x, q4.x, a00); a01 = fmaf(k0[i].y, q4.y, a01);
                a02 = fmaf(k0[i].z, q4.z, a02); a03 = fmaf(k0[i].w, q4.w, a03);
                a10 = fmaf(k1[i].x, q4.x, a10); a11 = fmaf(k1[i].y, q4.y, a11);
                a12 = fmaf(k1[i].z, q4.z, a12); a13 = fmaf(k1[i].w, q4.w, a13);
            }
            float s0 = (a00 + a01) + (a02 + a03);
            float s1 = (a10 + a11) + (a12 + a13);
            s0 += __shfl_xor(s0, 16); s0 += __shfl_xor(s0, 32);
            s1 += __shfl_xor(s1, 16); s1 += __shfl_xor(s1, 32);
            if (lane < 16) {
                s_p[m][t0 + lane]      = s0 * RSQRT_D;
                s_p[m][t0 + 16 + lane] = s1 * RSQRT_D;
            }
        }
    } else if (wid == 0) {   // tail chunk: 16 new rows, wave 0 only
        const float4* kp0 = (const float4*)(Kb + (size_t)tloc * DHEAD + ds * 32);
        float4 k0[8];
        #pragma unroll
        for (int i = 0; i < 8; ++i) k0[i] = kp0[i];
        #pragma unroll 4
        for (int m = 0; m < 16; ++m) {
            const float4* qp4 = (const float4*)(s_q + m * DHEAD + ds * 32);
            float a00 = 0.f, a01 = 0.f, a02 = 0.f, a03 = 0.f;
            #pragma unroll
            for (int i = 0; i < 8; ++i) {
                float4 q4 = qp4[i];
                a00 = fmaf(k0[i].x, q4.x, a00); a01 = fmaf(k0[i].y, q4.y, a01);
                a02 = fmaf(k0[i].z, q4.z, a02); a03 = fmaf(k0[i].w, q4.w, a03);
            }
            float s0 = (a00 + a01) + (a02 + a03);
            s0 += __shfl_xor(s0, 16); s0 += __shfl_xor(s0, 32);
            if (lane < 16) s_p[m][lane] = s0 * RSQRT_D;
        }
    }
    __syncthreads();

    // ---- phase 2: chunk-local softmax over t for each m (16 lanes per m) ----
    int m2 = tid >> 4, tl = tid & 15;
    float mx = -1e30f;
    for (int t = tl; t < nT; t += 16) mx = fmaxf(mx, s_p[m2][t]);
    #pragma unroll
    for (int o = 8; o; o >>= 1) mx = fmaxf(mx, __shfl_xor(mx, o));
    float sm = 0.f;
    for (int t = tl; t < nT; t += 16) {
        float p = expf(s_p[m2][t] - mx);
        s_p[m2][t] = p;
        sm += p;
    }
    #pragma unroll
    for (int o = 8; o; o >>= 1) sm += __shfl_xor(sm, o);
    if (tl == 0) {
        float* msp = ms + ((size_t)(h * NCH + c) * 16 + m2) * 2;
        msp[0] = mx; msp[1] = sm;
    }
    __syncthreads();

    // ---- phase 3: partial PV, tiled by 8 t; wave handles 4 m ----
    int mg = wid * 4;
    float2 acc2[4] = {{0.f,0.f},{0.f,0.f},{0.f,0.f},{0.f,0.f}};
    for (int t = 0; t < nT; t += 8) {
        float2 vv[8];
        #pragma unroll
        for (int i = 0; i < 8; ++i)
            vv[i] = *(const float2*)(Vb + (size_t)(t + i) * DHEAD + 2 * lane);
        float4 p0[4], p1[4];
        #pragma unroll
        for (int mm = 0; mm < 4; ++mm) {
            p0[mm] = *(const float4*)&s_p[mg + mm][t];
            p1[mm] = *(const float4*)&s_p[mg + mm][t + 4];
        }
        #pragma unroll
        for (int mm = 0; mm < 4; ++mm) {
            acc2[mm].x = fmaf(p0[mm].x, vv[0].x, acc2[mm].x);
            acc2[mm].y = fmaf(p0[mm].x, vv[0].y, acc2[mm].y);
            acc2[mm].x = fmaf(p0[mm].y, vv[1].x, acc2[mm].x);
            acc2[mm].y = fmaf(p0[mm].y, vv[1].y, acc2[mm].y);
            acc2[mm].x = fmaf(p0[mm].z, vv[2].x, acc2[mm].x);
            acc2[mm].y = fmaf(p0[mm].z, vv[2].y, acc2[mm].y);
            acc2[mm].x = fmaf(p0[mm].w, vv[3].x, acc2[mm].x);
            acc2[mm].y = fmaf(p0[mm].w, vv[3].y, acc2[mm].y);
            acc2[mm].x = fmaf(p1[mm].x, vv[4].x, acc2[mm].x);
            acc2[mm].y = fmaf(p1[mm].x, vv[4].y, acc2[mm].y);
            acc2[mm].x = fmaf(p1[mm].y, vv[5].x, acc2[mm].x);
            acc2[mm].y = fmaf(p1[mm].y, vv[5].y, acc2[mm].y);
            acc2[mm].x = fmaf(p1[mm].z, vv[6].x, acc2[mm].x);
            acc2[mm].y = fmaf(p1[mm].z, vv[6].y, acc2[mm].y);
            acc2[mm].x = fmaf(p1[mm].w, vv[7].x, acc2[mm].x);
            acc2[mm].y = fmaf(p1[mm].w, vv[7].y, acc2[mm].y);
        }
    }
    #pragma unroll
    for (int mm = 0; mm < 4; ++mm) {
        float* dp = part + ((size_t)(h * NCH + c) * 16 + mg + mm) * DHEAD + 2 * lane;
        dp[0] = acc2[mm].x; dp[1] = acc2[mm].y;
    }
}

// ---------------- combine chunk partials: block per (head, 16-d slice) -------
__global__ __launch_bounds__(256) void k_combine(const float* __restrict__ part,
                                                 const float* __restrict__ ms,
                                                 float* __restrict__ attnout) {
    __shared__ float scale[16][NCH];
    int h = blockIdx.x >> 3, dblk = blockIdx.x & 7;
    int tid = threadIdx.x;
    if (tid < 16) {
        int m = tid;
        float gmax = -1e30f;
        for (int c = 0; c < NCH; ++c)
            gmax = fmaxf(gmax, ms[((size_t)(h * NCH + c) * 16 + m) * 2]);
        float denom = 0.f;
        for (int c = 0; c < NCH; ++c) {
            const float* msp = ms + ((size_t)(h * NCH + c) * 16 + m) * 2;
            denom += msp[1] * expf(msp[0] - gmax);
        }
        float inv = 1.f / denom;
        for (int c = 0; c < NCH; ++c) {
            const float* msp = ms + ((size_t)(h * NCH + c) * 16 + m) * 2;
            scale[m][c] = expf(msp[0] - gmax) * inv;
        }
    }
    __syncthreads();
    int m = tid >> 4, dd = tid & 15;
    int d = dblk * 16 + dd;
    const float* pp = part + ((size_t)h * NCH * 16 + m) * DHEAD + d;
    float acc = 0.f;
    for (int c = 0; c < NCH; ++c)
        acc = fmaf(pp[(size_t)c * 16 * DHEAD], scale[m][c], acc);
    attnout[(size_t)m * NDIM + h * DHEAD + d] = acc;
}

// ---------------- launcher ----------------
extern "C" void kernel_launch(void* const* d_in, const int* in_sizes, int n_in,
                              void* d_out, int out_size, void* d_ws, size_t ws_size,
                              hipStream_t stream) {
    const float* X      = (const float*)d_in[0];
    const float* ln1_g  = (const float*)d_in[1];
    const float* ln1_b  = (const float*)d_in[2];
    const float* Wq     = (const float*)d_in[3];
    const float* Wk     = (const float*)d_in[4];
    const float* Wv     = (const float*)d_in[5];
    const float* Wo     = (const float*)d_in[6];
    const float* ln2_g  = (const float*)d_in[7];
    const float* ln2_b  = (const float*)d_in[8];
    const float* Wup    = (const float*)d_in[9];
    const float* Wdown  = (const float*)d_in[10];
    const float* cacheK = (const float*)d_in[11];
    const float* cacheV = (const float*)d_in[12];
    float* out = (float*)d_out;

    float* ws = (float*)d_ws;
    float* Xn1    = ws;                       // 32768
    float* qws    = Xn1 + 32768;              // 32768
    float* kws    = qws + 32768;              // 32768
    float* vws    = kws + 32768;              // 32768
    float* partb  = vws + 32768;              // 16*65*16*128 = 2129920
    float* msb    = partb + 2129920;          // 16*65*16*2   = 33280
    float* attn_o = msb + 33280;              // 32768
    float* X2     = attn_o + 32768;           // 32768
    float* Xn2    = X2 + 32768;               // 32768
    float* ffnh   = Xn2 + 32768;              // 131072

    k_ln<<<M_TOK, 256, 0, stream>>>(X, ln1_g, ln1_b, Xn1);
    k_qkv<<<1536, 256, 0, stream>>>(Xn1, Wq, Wk, Wv, qws, kws, vws);
    k_attn<<<NHEAD * NCH, 256, 0, stream>>>(cacheK, cacheV, qws, kws, vws, partb, msb);
    k_combine<<<NHEAD * 8, 256, 0, stream>>>(partb, msb, attn_o);
    k_resid<2048><<<512, 256, 0, stream>>>(attn_o, Wo, X, X2);
    k_ln<<<M_TOK, 256, 0, stream>>>(X2, ln2_g, ln2_b, Xn2);
    k_up<<<2048, 256, 0, stream>>>(Xn2, Wup, ffnh);
    k_resid<8192><<<512, 256, 0, stream>>>(ffnh, Wdown, X2, out);
}